// Round 8
// baseline (472.479 us; speedup 1.0000x reference)
//
#include <hip/hip_runtime.h>

#define N 8192
#define DIN 128
#define DH 48
#define NSPLIT 16
#define SPAN (N / NSPLIT)    // 512 j per block
#define MTK 64               // rows per k_gat block (4 waves x 16 rows)
#define ACC_STRIDE 64        // 48 dims + lsum@48 + 15 unused (MFMA N-tile padding)
#define RB 32                // rows per k_mlp block

typedef _Float16 half8 __attribute__((ext_vector_type(8)));
typedef float f32x4 __attribute__((ext_vector_type(4)));

// ---------------- Kernel 1a: Wh = x @ Wgat^T  [8192,128]x[48,128] -> [8192,48]
__global__ __launch_bounds__(256) void k_wh(const float* __restrict__ x,
                                            const float* __restrict__ Wg,
                                            float* __restrict__ Wh) {
    __shared__ float wT[DIN * DH];  // transposed: wT[k*DH + c] = Wg[c*DIN + k]
    int t = threadIdx.x;
    for (int e = t; e < DIN * DH; e += 256) {
        int c = e / DIN, k = e % DIN;
        wT[k * DH + c] = Wg[e];
    }
    __syncthreads();
    int o = blockIdx.x * 256 + t;      // o < 8192*48
    int r = o / DH, c = o % DH;
    const float4* xr = (const float4*)(x + (size_t)r * DIN);
    float acc = 0.f;
    #pragma unroll 8
    for (int k4 = 0; k4 < DIN / 4; ++k4) {
        float4 xv = xr[k4];
        int kb = k4 * 4;
        acc += xv.x * wT[(kb + 0) * DH + c];
        acc += xv.y * wT[(kb + 1) * DH + c];
        acc += xv.z * wT[(kb + 2) * DH + c];
        acc += xv.w * wT[(kb + 3) * DH + c];
    }
    Wh[o] = acc;
}

// ---------------- Kernel 1b: s = Wh @ a^T
__global__ __launch_bounds__(256) void k_s(const float* __restrict__ Wh,
                                           const float* __restrict__ a,
                                           float* __restrict__ s) {
    int r = blockIdx.x * 256 + threadIdx.x;
    const float4* wr = (const float4*)(Wh + (size_t)r * DH);
    const float4* av = (const float4*)a;
    float acc = 0.f;
    #pragma unroll
    for (int k4 = 0; k4 < DH / 4; ++k4) {
        float4 w = wr[k4]; float4 aa = av[k4];
        acc += w.x * aa.x + w.y * aa.y + w.z * aa.z + w.w * aa.w;
    }
    s[r] = acc;
}

// ---------------- Kernel 1c: WhT16[d][j], d in [0,64):
//   d<48 : (f16)Wh[j][d]   (same RTN cast as old wS staging)
//   d=48 : 1.0  (ones column -> lsum)
//   d>48 : 0.0  (MFMA N-tile zero padding)
__global__ __launch_bounds__(256) void k_tr(const float* __restrict__ Wh,
                                            _Float16* __restrict__ WhT16) {
    int o = blockIdx.x * 256 + threadIdx.x;   // o < 64*8192, d-major
    int d = o >> 13, j = o & 8191;
    _Float16 v;
    if (d < DH)       v = (_Float16)Wh[(size_t)j * DH + d];
    else if (d == DH) v = (_Float16)1.0f;
    else              v = (_Float16)0.0f;
    WhT16[o] = v;
}

// ---------------- Kernel 2: fused masked-softmax attention with
// PAGE-SEQUENTIAL adj streaming.
//
// Diagnosis arc: k_gat pinned at ~1.9 TB/s (30% of 6.3) across pipelining
// (R4), occupancy (R5), channel rotation (R6), and load width (R7) -- all
// flat. The invariant: every load covered a 256-B adj segment at 32-KB
// stride (KC=64 j-window) -> one DRAM page opened per 256 B used. This
// kernel reads each adj row CONTIGUOUSLY across the whole 512-j split
// (2 KB = a full page, as two 1-KB wave-instructions, 64 lanes j-major),
// computes P for the full span, and stores into a 64-KB LDS P-buffer;
// the MFMA phase then sweeps 8 K-chunks from LDS.
//
// Geometry: block = 64 rows x 512 j; 4 waves x 16 rows, strictly per-wave
// pS/row slices -> still BARRIER-FREE. pS[64][512] f16 = 64 KB -> 2
// blocks/CU (2 waves/SIMD: phase A of one block overlaps MFMA of the
// other). Row stride 1024 B would be a 16-way bank conflict on the MFMA
// ds_read_b128 -> XOR swizzle byte ^= ((row&7)<<4) on BOTH write and read
// (T2 discipline). P hits identical RTN points; chunks accumulate in the
// same order -> bit-identical output vs R7.
__global__ __launch_bounds__(256, 2) void k_gat(const int* __restrict__ adj,
                                                const _Float16* __restrict__ WhT16,
                                                const float* __restrict__ s,
                                                float* __restrict__ accWs) {
    __shared__ _Float16 pS[MTK][SPAN];  // 64 KB, XOR-swizzled rows
    int t = threadIdx.x;
    int tile = blockIdx.x & 127;       // 128 row tiles of 64
    int split = blockIdx.x >> 7;       // 0..15
    int i0 = tile * MTK;
    int jbase = split * SPAN;

    int lane = t & 63, w = t >> 6;
    int ln16 = lane & 15, kq = lane >> 4;   // MFMA lane decomposition
    int rw = w * 16;                        // wave's first row within block

    // s values: 16 wave-uniform row scores (scalar loads) + per-lane col scores
    float srw[16];
    #pragma unroll
    for (int k = 0; k < 16; ++k) srw[k] = s[i0 + rw + k];
    float4 sj0 = *(const float4*)(s + jbase + 4 * lane);         // j [0,256)
    float4 sj1 = *(const float4*)(s + jbase + 256 + 4 * lane);   // j [256,512)

    // ---- phase A: stream adj rows (2 KB contiguous each), P -> pS (swizzled)
    const int* adjW = adj + (size_t)(i0 + rw) * N + jbase;
    #pragma unroll
    for (int r = 0; r < 16; ++r) {
        int4 a0 = *(const int4*)(adjW + (size_t)r * N + 4 * lane);        // 1 KB/instr
        int4 a1 = *(const int4*)(adjW + (size_t)r * N + 256 + 4 * lane);  // 1 KB/instr
        float sr = srw[r];
        union { _Float16 h[4]; double d; } pk0, pk1;
        {
            float e0 = sr + sj0.x, e1 = sr + sj0.y, e2 = sr + sj0.z, e3 = sr + sj0.w;
            e0 = fmaxf(e0, 0.2f * e0); e1 = fmaxf(e1, 0.2f * e1);   // LeakyReLU(0.2)
            e2 = fmaxf(e2, 0.2f * e2); e3 = fmaxf(e3, 0.2f * e3);
            pk0.h[0] = (_Float16)(a0.x ? __expf(e0) : 0.f);          // masked -> 0
            pk0.h[1] = (_Float16)(a0.y ? __expf(e1) : 0.f);          // RTN
            pk0.h[2] = (_Float16)(a0.z ? __expf(e2) : 0.f);
            pk0.h[3] = (_Float16)(a0.w ? __expf(e3) : 0.f);
        }
        {
            float e0 = sr + sj1.x, e1 = sr + sj1.y, e2 = sr + sj1.z, e3 = sr + sj1.w;
            e0 = fmaxf(e0, 0.2f * e0); e1 = fmaxf(e1, 0.2f * e1);
            e2 = fmaxf(e2, 0.2f * e2); e3 = fmaxf(e3, 0.2f * e3);
            pk1.h[0] = (_Float16)(a1.x ? __expf(e0) : 0.f);
            pk1.h[1] = (_Float16)(a1.y ? __expf(e1) : 0.f);
            pk1.h[2] = (_Float16)(a1.z ? __expf(e2) : 0.f);
            pk1.h[3] = (_Float16)(a1.w ? __expf(e3) : 0.f);
        }
        // swizzled 8-B stores: f16-col 4*lane -> byte 8*lane, XOR bits 4-6
        char* rowp = (char*)&pS[rw + r][0];
        int swz = (r & 7) << 4;
        *(double*)(rowp + ((8 * lane) ^ swz)) = pk0.d;
        *(double*)(rowp + (512 + ((8 * lane) ^ swz))) = pk1.d;
    }

    // ---- MFMA phase: sweep 8 K-chunks from pS (own wave's writes: lgkmcnt
    // only, no barrier). B fragments direct from L2-hot WhT16.
    f32x4 acc[4];
    #pragma unroll
    for (int nt = 0; nt < 4; ++nt) acc[nt] = (f32x4){0.f, 0.f, 0.f, 0.f};

    const char* arp = (const char*)&pS[rw + ln16][0];
    const int aswz = (ln16 & 7) << 4;
    #pragma unroll
    for (int c = 0; c < 8; ++c) {
        int j0 = jbase + c * 64;
        half8 bf[2][4];
        #pragma unroll
        for (int kt = 0; kt < 2; ++kt)
            #pragma unroll
            for (int nt = 0; nt < 4; ++nt)
                bf[kt][nt] = *(const half8*)&WhT16[(size_t)(nt * 16 + ln16) * N
                                                  + j0 + kt * 32 + kq * 8];
        #pragma unroll
        for (int kt = 0; kt < 2; ++kt) {
            half8 a = *(const half8*)(arp + ((c * 128 + kt * 64 + kq * 16) ^ aswz));
            #pragma unroll
            for (int nt = 0; nt < 4; ++nt)
                acc[nt] = __builtin_amdgcn_mfma_f32_16x16x32_f16(
                    a, bf[kt][nt], acc[nt], 0, 0, 0);
        }
    }

    // ---- epilogue: C/D layout col=lane&15, row=kq*4+reg
    size_t rbase = (size_t)split * N + i0 + rw;
    #pragma unroll
    for (int nt = 0; nt < 4; ++nt) {
        int col = nt * 16 + ln16;
        if (nt == 3 && ln16 != 0) continue;   // only col 48 (lsum) useful
        #pragma unroll
        for (int reg = 0; reg < 4; ++reg) {
            int row = kq * 4 + reg;
            accWs[(rbase + row) * ACC_STRIDE + col] = acc[nt][reg];
        }
    }
}

// ---------------- Kernel 3: reduce splits + LayerNorm + MFMA MLP 48->256->128->32
__global__ __launch_bounds__(256) void k_mlp(const float* __restrict__ accWs,
                                             const float* __restrict__ gamma,
                                             const float* __restrict__ beta,
                                             const float* __restrict__ W1, const float* __restrict__ b1,
                                             const float* __restrict__ W2, const float* __restrict__ b2,
                                             const float* __restrict__ W3, const float* __restrict__ b3,
                                             float* __restrict__ out) {
    __shared__ float hacc[RB * 49];
    __shared__ _Float16 hN[RB * 72];    // [32][72] f16, cols 48..71 zero (K pad)
    __shared__ _Float16 h1[RB * 264];   // [32][264] f16
    __shared__ float h2[RB * 132];      // [32][132] f32
    int t = threadIdx.x;
    int r0 = blockIdx.x * RB;
    int lane = t & 63, w = t >> 6;
    int ln16 = lane & 15, kq = lane >> 4;

    // reduce K-split partials (d: 0..47 dims, 48 = lsum)
    for (int e = t; e < RB * 49; e += 256) {
        int r = e / 49, d = e % 49;
        size_t base = (size_t)(r0 + r) * ACC_STRIDE + d;
        float v = 0.f;
        #pragma unroll
        for (int sp = 0; sp < NSPLIT; ++sp)
            v += accWs[(size_t)sp * N * ACC_STRIDE + base];
        hacc[e] = v;
    }
    __syncthreads();

    // LayerNorm (two-pass), h' = acc / l ; store f16 for MFMA A-operand
    if (t < RB) {
        float invl = 1.f / hacc[t * 49 + 48];
        float sum = 0.f;
        for (int d = 0; d < DH; ++d) sum += hacc[t * 49 + d];
        float mean = sum * invl * (1.f / DH);
        float var = 0.f;
        for (int d = 0; d < DH; ++d) {
            float dv = hacc[t * 49 + d] * invl - mean;
            var += dv * dv;
        }
        var *= (1.f / DH);
        float rs = rsqrtf(var + 1e-5f);
        for (int d = 0; d < DH; ++d) {
            float hv = (hacc[t * 49 + d] * invl - mean) * rs;
            hN[t * 72 + d] = (_Float16)(hv * gamma[d] + beta[d]);
        }
        for (int d = DH; d < 72; ++d) hN[t * 72 + d] = (_Float16)0.f;
    }
    __syncthreads();

    // MLP1 (MFMA): M=32, N=256, K=48 padded to 64. wave w owns N-tiles w*4..w*4+3
    {
        f32x4 acc1[2][4];
        #pragma unroll
        for (int mt = 0; mt < 2; ++mt)
            #pragma unroll
            for (int nt = 0; nt < 4; ++nt) acc1[mt][nt] = (f32x4){0.f, 0.f, 0.f, 0.f};
        #pragma unroll
        for (int kt = 0; kt < 2; ++kt) {
            int k = kt * 32 + kq * 8;
            half8 a[2];
            #pragma unroll
            for (int mt = 0; mt < 2; ++mt)
                a[mt] = *(const half8*)&hN[(mt * 16 + ln16) * 72 + k];
            #pragma unroll
            for (int ntl = 0; ntl < 4; ++ntl) {
                int n = (w * 4 + ntl) * 16 + ln16;
                half8 b;
                #pragma unroll
                for (int i = 0; i < 8; ++i) b[i] = (_Float16)0.f;
                if (k < DH) {   // k in {0,8,16,24,32,40}; >=48 stays zero
                    float4 lo = *(const float4*)(W1 + n * DH + k);
                    float4 hi = *(const float4*)(W1 + n * DH + k + 4);
                    b[0] = (_Float16)lo.x; b[1] = (_Float16)lo.y;
                    b[2] = (_Float16)lo.z; b[3] = (_Float16)lo.w;
                    b[4] = (_Float16)hi.x; b[5] = (_Float16)hi.y;
                    b[6] = (_Float16)hi.z; b[7] = (_Float16)hi.w;
                }
                #pragma unroll
                for (int mt = 0; mt < 2; ++mt)
                    acc1[mt][ntl] = __builtin_amdgcn_mfma_f32_16x16x32_f16(
                        a[mt], b, acc1[mt][ntl], 0, 0, 0);
            }
        }
        #pragma unroll
        for (int mt = 0; mt < 2; ++mt)
            #pragma unroll
            for (int ntl = 0; ntl < 4; ++ntl) {
                int col = (w * 4 + ntl) * 16 + ln16;
                float bias = b1[col];
                #pragma unroll
                for (int reg = 0; reg < 4; ++reg) {
                    int row = mt * 16 + kq * 4 + reg;
                    float v = acc1[mt][ntl][reg] + bias;
                    h1[row * 264 + col] = (_Float16)fmaxf(v, 0.f);
                }
            }
    }
    __syncthreads();

    // MLP2 (MFMA): M=32, N=128, K=256. wave w owns N-tiles w*2, w*2+1
    {
        f32x4 acc2[2][2];
        #pragma unroll
        for (int mt = 0; mt < 2; ++mt)
            #pragma unroll
            for (int nt = 0; nt < 2; ++nt) acc2[mt][nt] = (f32x4){0.f, 0.f, 0.f, 0.f};
        #pragma unroll
        for (int kt = 0; kt < 8; ++kt) {
            int k = kt * 32 + kq * 8;
            half8 a[2];
            #pragma unroll
            for (int mt = 0; mt < 2; ++mt)
                a[mt] = *(const half8*)&h1[(mt * 16 + ln16) * 264 + k];
            #pragma unroll
            for (int ntl = 0; ntl < 2; ++ntl) {
                int n = (w * 2 + ntl) * 16 + ln16;
                float4 lo = *(const float4*)(W2 + n * 256 + k);
                float4 hi = *(const float4*)(W2 + n * 256 + k + 4);
                half8 b;
                b[0] = (_Float16)lo.x; b[1] = (_Float16)lo.y;
                b[2] = (_Float16)lo.z; b[3] = (_Float16)lo.w;
                b[4] = (_Float16)hi.x; b[5] = (_Float16)hi.y;
                b[6] = (_Float16)hi.z; b[7] = (_Float16)hi.w;
                #pragma unroll
                for (int mt = 0; mt < 2; ++mt)
                    acc2[mt][ntl] = __builtin_amdgcn_mfma_f32_16x16x32_f16(
                        a[mt], b, acc2[mt][ntl], 0, 0, 0);
            }
        }
        #pragma unroll
        for (int mt = 0; mt < 2; ++mt)
            #pragma unroll
            for (int ntl = 0; ntl < 2; ++ntl) {
                int col = (w * 2 + ntl) * 16 + ln16;
                float bias = b2[col];
                #pragma unroll
                for (int reg = 0; reg < 4; ++reg) {
                    int row = mt * 16 + kq * 4 + reg;
                    h2[row * 132 + col] = fmaxf(acc2[mt][ntl][reg] + bias, 0.f);
                }
            }
    }
    __syncthreads();

    // MLP3: 128 -> 32 (scalar; small)
    {
        int c = t & 31;
        int g = t >> 5;
        int rb = g * 4;
        float acc[4];
        float bias = b3[c];
        #pragma unroll
        for (int r = 0; r < 4; ++r) acc[r] = bias;
        const float4* wrow = (const float4*)(W3 + c * 128);
        for (int k4 = 0; k4 < 32; ++k4) {
            float4 wv = wrow[k4];
            #pragma unroll
            for (int r = 0; r < 4; ++r) {
                const float4 hv = *(const float4*)(&h2[(rb + r) * 132 + k4 * 4]);
                acc[r] += wv.x * hv.x + wv.y * hv.y + wv.z * hv.z + wv.w * hv.w;
            }
        }
        #pragma unroll
        for (int r = 0; r < 4; ++r)
            out[(size_t)(r0 + rb + r) * 32 + c] = acc[r];
    }
}

extern "C" void kernel_launch(void* const* d_in, const int* in_sizes, int n_in,
                              void* d_out, int out_size, void* d_ws, size_t ws_size,
                              hipStream_t stream) {
    const float* x     = (const float*)d_in[0];
    const int*   adj   = (const int*)d_in[1];
    const float* Wg    = (const float*)d_in[2];
    const float* a     = (const float*)d_in[3];
    const float* gamma = (const float*)d_in[4];
    const float* beta  = (const float*)d_in[5];
    const float* W1    = (const float*)d_in[6];
    const float* b1    = (const float*)d_in[7];
    const float* W2    = (const float*)d_in[8];
    const float* b2    = (const float*)d_in[9];
    const float* W3    = (const float*)d_in[10];
    const float* b3    = (const float*)d_in[11];
    float* out = (float*)d_out;

    float* ws = (float*)d_ws;
    float* Wh       = ws;                          // 8192*48 f32
    float* s        = ws + (size_t)N * DH;         // 8192 f32
    _Float16* WhT16 = (_Float16*)(s + N);          // 64*8192 f16 (16B-aligned)
    float* accWs    = (float*)((char*)WhT16 + (size_t)64 * N * sizeof(_Float16));
                                                   // NSPLIT*8192*64 f32 = 33.5 MB

    k_wh<<<N * DH / 256, 256, 0, stream>>>(x, Wg, Wh);
    k_s<<<N / 256, 256, 0, stream>>>(Wh, a, s);
    k_tr<<<64 * N / 256, 256, 0, stream>>>(Wh, WhT16);
    k_gat<<<128 * NSPLIT, 256, 0, stream>>>(adj, WhT16, s, accWs);
    k_mlp<<<N / RB, 256, 0, stream>>>(accWs, gamma, beta, W1, b1, W2, b2, W3, b3, out);
}

// Round 9
// 467.434 us; speedup vs baseline: 1.0108x; 1.0108x over previous
//
#include <hip/hip_runtime.h>

#define N 8192
#define DIN 128
#define DH 48
#define NSPLIT 16
#define SPAN (N / NSPLIT)    // 512 j per k_gat block
#define NCHUNK (SPAN / 64)   // 8 K-chunks of 64
#define NW64 (N / 64)        // 128 mask words per row
#define ACC_STRIDE 64        // 48 dims + lsum@48 + 15 unused (MFMA N-tile padding)
#define RB 32                // rows per k_mlp block

typedef _Float16 half8 __attribute__((ext_vector_type(8)));
typedef float f32x4 __attribute__((ext_vector_type(4)));

// ---------------- Kernel 1a: Wh = x @ Wgat^T  [8192,128]x[48,128] -> [8192,48]
__global__ __launch_bounds__(256) void k_wh(const float* __restrict__ x,
                                            const float* __restrict__ Wg,
                                            float* __restrict__ Wh) {
    __shared__ float wT[DIN * DH];  // transposed: wT[k*DH + c] = Wg[c*DIN + k]
    int t = threadIdx.x;
    for (int e = t; e < DIN * DH; e += 256) {
        int c = e / DIN, k = e % DIN;
        wT[k * DH + c] = Wg[e];
    }
    __syncthreads();
    int o = blockIdx.x * 256 + t;      // o < 8192*48
    int r = o / DH, c = o % DH;
    const float4* xr = (const float4*)(x + (size_t)r * DIN);
    float acc = 0.f;
    #pragma unroll 8
    for (int k4 = 0; k4 < DIN / 4; ++k4) {
        float4 xv = xr[k4];
        int kb = k4 * 4;
        acc += xv.x * wT[(kb + 0) * DH + c];
        acc += xv.y * wT[(kb + 1) * DH + c];
        acc += xv.z * wT[(kb + 2) * DH + c];
        acc += xv.w * wT[(kb + 3) * DH + c];
    }
    Wh[o] = acc;
}

// ---------------- Kernel 1b: s = Wh @ a^T
__global__ __launch_bounds__(256) void k_s(const float* __restrict__ Wh,
                                           const float* __restrict__ a,
                                           float* __restrict__ s) {
    int r = blockIdx.x * 256 + threadIdx.x;
    const float4* wr = (const float4*)(Wh + (size_t)r * DH);
    const float4* av = (const float4*)a;
    float acc = 0.f;
    #pragma unroll
    for (int k4 = 0; k4 < DH / 4; ++k4) {
        float4 w = wr[k4]; float4 aa = av[k4];
        acc += w.x * aa.x + w.y * aa.y + w.z * aa.z + w.w * aa.w;
    }
    s[r] = acc;
}

// ---------------- Kernel 1c: WhT16[d][j], d in [0,64):
//   d<48 : (f16)Wh[j][d]   (same RTN cast as original staging)
//   d=48 : 1.0  (ones column -> lsum)
//   d>48 : 0.0  (MFMA N-tile zero padding)
__global__ __launch_bounds__(256) void k_tr(const float* __restrict__ Wh,
                                            _Float16* __restrict__ WhT16) {
    int o = blockIdx.x * 256 + threadIdx.x;   // o < 64*8192, d-major
    int d = o >> 13, j = o & 8191;
    _Float16 v;
    if (d < DH)       v = (_Float16)Wh[(size_t)j * DH + d];
    else if (d == DH) v = (_Float16)1.0f;
    else              v = (_Float16)0.0f;
    WhT16[o] = v;
}

// ---------------- Kernel 1d: adj bit-pack. mask64[r*NW64+c] bit b = adj[r][c*64+b]!=0.
// Pure stream: 256 MiB read + 8 MiB write, no LDS, tiny VGPR -> runs at
// stream BW with full occupancy. This removes 97% of k_gat's HBM traffic.
__global__ __launch_bounds__(256) void k_pack(const int* __restrict__ adj,
                                              unsigned long long* __restrict__ mask) {
    size_t o = (size_t)blockIdx.x * 256 + threadIdx.x;   // o < N*N/64
    const int4* p = (const int4*)(adj + o * 64);
    unsigned long long m = 0;
    #pragma unroll
    for (int g = 0; g < 16; ++g) {
        int4 a = p[g];
        m |= ((unsigned long long)(a.x != 0)) << (4 * g + 0);
        m |= ((unsigned long long)(a.y != 0)) << (4 * g + 1);
        m |= ((unsigned long long)(a.z != 0)) << (4 * g + 2);
        m |= ((unsigned long long)(a.w != 0)) << (4 * g + 3);
    }
    mask[o] = m;
}

// P-fragment builder: 8 consecutive j's of one row, masked exp, f16 RTN --
// identical rounding points to all previous passing rounds.
__device__ __forceinline__ half8 mk_afrag(float si, const float* __restrict__ sjp,
                                          unsigned b8) {
    float4 lo = *(const float4*)sjp;
    float4 hi = *(const float4*)(sjp + 4);
    half8 a;
    float e;
    e = si + lo.x; e = fmaxf(e, 0.2f * e); a[0] = (_Float16)((b8 & 1u)   ? __expf(e) : 0.f);
    e = si + lo.y; e = fmaxf(e, 0.2f * e); a[1] = (_Float16)((b8 & 2u)   ? __expf(e) : 0.f);
    e = si + lo.z; e = fmaxf(e, 0.2f * e); a[2] = (_Float16)((b8 & 4u)   ? __expf(e) : 0.f);
    e = si + lo.w; e = fmaxf(e, 0.2f * e); a[3] = (_Float16)((b8 & 8u)   ? __expf(e) : 0.f);
    e = si + hi.x; e = fmaxf(e, 0.2f * e); a[4] = (_Float16)((b8 & 16u)  ? __expf(e) : 0.f);
    e = si + hi.y; e = fmaxf(e, 0.2f * e); a[5] = (_Float16)((b8 & 32u)  ? __expf(e) : 0.f);
    e = si + hi.z; e = fmaxf(e, 0.2f * e); a[6] = (_Float16)((b8 & 64u)  ? __expf(e) : 0.f);
    e = si + hi.w; e = fmaxf(e, 0.2f * e); a[7] = (_Float16)((b8 & 128u) ? __expf(e) : 0.f);
    return a;
}

// ---------------- Kernel 2: fused masked-softmax attention, IN-REGISTER P.
//
// Diagnosis arc (R1..R8): every LDS-staged variant pinned at 1-2 TB/s with
// ALL pipes idle -- latency-serialized adj loads at ~8 waves/CU (LDS-capped
// occupancy). R8's counters: 991 GB/s, MfmaUtil 2%, VALU 12%, occ 22%.
// Fix: adj -> 8 MiB bitmask (k_pack), and each lane (ln16,kq) computes its
// MFMA A-fragment P[row][j0+kt*32+kq*8+0..7] directly in registers from an
// 8-bit mask slice + s values. NO LDS AT ALL, no barriers, no swizzle;
// launch_bounds(256,4) -> ~16 waves/CU. Mask + s + WhT16 are L2-hot.
// Same __expf / f16-RTN points -> same absmax as all passing rounds.
__global__ __launch_bounds__(256, 4) void k_gat(const unsigned long long* __restrict__ mask,
                                                const _Float16* __restrict__ WhT16,
                                                const float* __restrict__ s,
                                                float* __restrict__ accWs) {
    int t = threadIdx.x;
    int tile = blockIdx.x & 63;        // 64 row tiles of 128
    int split = blockIdx.x >> 6;       // 0..15
    int i0 = tile * 128;
    int jbase = split * SPAN;

    int lane = t & 63, w = t >> 6;
    int ln16 = lane & 15, kq = lane >> 4;   // MFMA lane decomposition
    int rw = w * 32;                        // wave's 32 rows = 2 M-tiles

    // per-lane row scores + mask row pointers (mask is L2-hot: 8 MiB total)
    float si0 = s[i0 + rw + ln16];
    float si1 = s[i0 + rw + 16 + ln16];
    const unsigned long long* mrow0 =
        mask + (size_t)(i0 + rw + ln16) * NW64 + split * NCHUNK;
    const unsigned long long* mrow1 = mrow0 + (size_t)16 * NW64;

    f32x4 acc[2][4];
    #pragma unroll
    for (int a0 = 0; a0 < 2; ++a0)
        #pragma unroll
        for (int b0 = 0; b0 < 4; ++b0) acc[a0][b0] = (f32x4){0.f, 0.f, 0.f, 0.f};

    #pragma unroll 2
    for (int c = 0; c < NCHUNK; ++c) {
        int j0 = jbase + c * 64;
        unsigned long long m0 = mrow0[c];
        unsigned long long m1 = mrow1[c];
        // ---- build A-fragments in registers (P never touches LDS)
        half8 af[2][2];   // [mtl][kt]
        #pragma unroll
        for (int kt = 0; kt < 2; ++kt) {
            const float* sjp = s + j0 + kt * 32 + kq * 8;
            int sh = kt * 32 + kq * 8;
            af[0][kt] = mk_afrag(si0, sjp, (unsigned)(m0 >> sh) & 0xffu);
            af[1][kt] = mk_afrag(si1, sjp, (unsigned)(m1 >> sh) & 0xffu);
        }
        // ---- B fragments from L2-hot WhT16 (1 MiB)
        half8 bf[2][4];
        #pragma unroll
        for (int kt = 0; kt < 2; ++kt)
            #pragma unroll
            for (int nt = 0; nt < 4; ++nt)
                bf[kt][nt] = *(const half8*)&WhT16[(size_t)(nt * 16 + ln16) * N
                                                  + j0 + kt * 32 + kq * 8];
        // ---- MFMA MAC
        __builtin_amdgcn_s_setprio(1);
        #pragma unroll
        for (int kt = 0; kt < 2; ++kt)
            #pragma unroll
            for (int mtl = 0; mtl < 2; ++mtl)
                #pragma unroll
                for (int nt = 0; nt < 4; ++nt)
                    acc[mtl][nt] = __builtin_amdgcn_mfma_f32_16x16x32_f16(
                        af[mtl][kt], bf[kt][nt], acc[mtl][nt], 0, 0, 0);
        __builtin_amdgcn_s_setprio(0);
    }

    // ---- epilogue: C/D layout col=lane&15, row=kq*4+reg
    size_t rbase = (size_t)split * N + i0;
    #pragma unroll
    for (int mtl = 0; mtl < 2; ++mtl) {
        #pragma unroll
        for (int nt = 0; nt < 4; ++nt) {
            int col = nt * 16 + ln16;
            if (nt == 3 && ln16 != 0) continue;   // only col 48 (lsum) useful
            #pragma unroll
            for (int reg = 0; reg < 4; ++reg) {
                int row = rw + mtl * 16 + kq * 4 + reg;
                accWs[(rbase + row) * ACC_STRIDE + col] = acc[mtl][nt][reg];
            }
        }
    }
}

// ---------------- Kernel 3: reduce splits + LayerNorm + MFMA MLP 48->256->128->32
__global__ __launch_bounds__(256) void k_mlp(const float* __restrict__ accWs,
                                             const float* __restrict__ gamma,
                                             const float* __restrict__ beta,
                                             const float* __restrict__ W1, const float* __restrict__ b1,
                                             const float* __restrict__ W2, const float* __restrict__ b2,
                                             const float* __restrict__ W3, const float* __restrict__ b3,
                                             float* __restrict__ out) {
    __shared__ float hacc[RB * 49];
    __shared__ _Float16 hN[RB * 72];    // [32][72] f16, cols 48..71 zero (K pad)
    __shared__ _Float16 h1[RB * 264];   // [32][264] f16
    __shared__ float h2[RB * 132];      // [32][132] f32
    int t = threadIdx.x;
    int r0 = blockIdx.x * RB;
    int lane = t & 63, w = t >> 6;
    int ln16 = lane & 15, kq = lane >> 4;

    // reduce K-split partials (d: 0..47 dims, 48 = lsum)
    for (int e = t; e < RB * 49; e += 256) {
        int r = e / 49, d = e % 49;
        size_t base = (size_t)(r0 + r) * ACC_STRIDE + d;
        float v = 0.f;
        #pragma unroll
        for (int sp = 0; sp < NSPLIT; ++sp)
            v += accWs[(size_t)sp * N * ACC_STRIDE + base];
        hacc[e] = v;
    }
    __syncthreads();

    // LayerNorm (two-pass), h' = acc / l ; store f16 for MFMA A-operand
    if (t < RB) {
        float invl = 1.f / hacc[t * 49 + 48];
        float sum = 0.f;
        for (int d = 0; d < DH; ++d) sum += hacc[t * 49 + d];
        float mean = sum * invl * (1.f / DH);
        float var = 0.f;
        for (int d = 0; d < DH; ++d) {
            float dv = hacc[t * 49 + d] * invl - mean;
            var += dv * dv;
        }
        var *= (1.f / DH);
        float rs = rsqrtf(var + 1e-5f);
        for (int d = 0; d < DH; ++d) {
            float hv = (hacc[t * 49 + d] * invl - mean) * rs;
            hN[t * 72 + d] = (_Float16)(hv * gamma[d] + beta[d]);
        }
        for (int d = DH; d < 72; ++d) hN[t * 72 + d] = (_Float16)0.f;
    }
    __syncthreads();

    // MLP1 (MFMA): M=32, N=256, K=48 padded to 64. wave w owns N-tiles w*4..w*4+3
    {
        f32x4 acc1[2][4];
        #pragma unroll
        for (int mt = 0; mt < 2; ++mt)
            #pragma unroll
            for (int nt = 0; nt < 4; ++nt) acc1[mt][nt] = (f32x4){0.f, 0.f, 0.f, 0.f};
        #pragma unroll
        for (int kt = 0; kt < 2; ++kt) {
            int k = kt * 32 + kq * 8;
            half8 a[2];
            #pragma unroll
            for (int mt = 0; mt < 2; ++mt)
                a[mt] = *(const half8*)&hN[(mt * 16 + ln16) * 72 + k];
            #pragma unroll
            for (int ntl = 0; ntl < 4; ++ntl) {
                int n = (w * 4 + ntl) * 16 + ln16;
                half8 b;
                #pragma unroll
                for (int i = 0; i < 8; ++i) b[i] = (_Float16)0.f;
                if (k < DH) {   // k in {0,8,16,24,32,40}; >=48 stays zero
                    float4 lo = *(const float4*)(W1 + n * DH + k);
                    float4 hi = *(const float4*)(W1 + n * DH + k + 4);
                    b[0] = (_Float16)lo.x; b[1] = (_Float16)lo.y;
                    b[2] = (_Float16)lo.z; b[3] = (_Float16)lo.w;
                    b[4] = (_Float16)hi.x; b[5] = (_Float16)hi.y;
                    b[6] = (_Float16)hi.z; b[7] = (_Float16)hi.w;
                }
                #pragma unroll
                for (int mt = 0; mt < 2; ++mt)
                    acc1[mt][ntl] = __builtin_amdgcn_mfma_f32_16x16x32_f16(
                        a[mt], b, acc1[mt][ntl], 0, 0, 0);
            }
        }
        #pragma unroll
        for (int mt = 0; mt < 2; ++mt)
            #pragma unroll
            for (int ntl = 0; ntl < 4; ++ntl) {
                int col = (w * 4 + ntl) * 16 + ln16;
                float bias = b1[col];
                #pragma unroll
                for (int reg = 0; reg < 4; ++reg) {
                    int row = mt * 16 + kq * 4 + reg;
                    float v = acc1[mt][ntl][reg] + bias;
                    h1[row * 264 + col] = (_Float16)fmaxf(v, 0.f);
                }
            }
    }
    __syncthreads();

    // MLP2 (MFMA): M=32, N=128, K=256. wave w owns N-tiles w*2, w*2+1
    {
        f32x4 acc2[2][2];
        #pragma unroll
        for (int mt = 0; mt < 2; ++mt)
            #pragma unroll
            for (int nt = 0; nt < 2; ++nt) acc2[mt][nt] = (f32x4){0.f, 0.f, 0.f, 0.f};
        #pragma unroll
        for (int kt = 0; kt < 8; ++kt) {
            int k = kt * 32 + kq * 8;
            half8 a[2];
            #pragma unroll
            for (int mt = 0; mt < 2; ++mt)
                a[mt] = *(const half8*)&h1[(mt * 16 + ln16) * 264 + k];
            #pragma unroll
            for (int ntl = 0; ntl < 2; ++ntl) {
                int n = (w * 2 + ntl) * 16 + ln16;
                float4 lo = *(const float4*)(W2 + n * 256 + k);
                float4 hi = *(const float4*)(W2 + n * 256 + k + 4);
                half8 b;
                b[0] = (_Float16)lo.x; b[1] = (_Float16)lo.y;
                b[2] = (_Float16)lo.z; b[3] = (_Float16)lo.w;
                b[4] = (_Float16)hi.x; b[5] = (_Float16)hi.y;
                b[6] = (_Float16)hi.z; b[7] = (_Float16)hi.w;
                #pragma unroll
                for (int mt = 0; mt < 2; ++mt)
                    acc2[mt][ntl] = __builtin_amdgcn_mfma_f32_16x16x32_f16(
                        a[mt], b, acc2[mt][ntl], 0, 0, 0);
            }
        }
        #pragma unroll
        for (int mt = 0; mt < 2; ++mt)
            #pragma unroll
            for (int ntl = 0; ntl < 2; ++ntl) {
                int col = (w * 2 + ntl) * 16 + ln16;
                float bias = b2[col];
                #pragma unroll
                for (int reg = 0; reg < 4; ++reg) {
                    int row = mt * 16 + kq * 4 + reg;
                    h2[row * 132 + col] = fmaxf(acc2[mt][ntl][reg] + bias, 0.f);
                }
            }
    }
    __syncthreads();

    // MLP3: 128 -> 32 (scalar; small)
    {
        int c = t & 31;
        int g = t >> 5;
        int rb = g * 4;
        float acc[4];
        float bias = b3[c];
        #pragma unroll
        for (int r = 0; r < 4; ++r) acc[r] = bias;
        const float4* wrow = (const float4*)(W3 + c * 128);
        for (int k4 = 0; k4 < 32; ++k4) {
            float4 wv = wrow[k4];
            #pragma unroll
            for (int r = 0; r < 4; ++r) {
                const float4 hv = *(const float4*)(&h2[(rb + r) * 132 + k4 * 4]);
                acc[r] += wv.x * hv.x + wv.y * hv.y + wv.z * hv.z + wv.w * hv.w;
            }
        }
        #pragma unroll
        for (int r = 0; r < 4; ++r)
            out[(size_t)(r0 + rb + r) * 32 + c] = acc[r];
    }
}

extern "C" void kernel_launch(void* const* d_in, const int* in_sizes, int n_in,
                              void* d_out, int out_size, void* d_ws, size_t ws_size,
                              hipStream_t stream) {
    const float* x     = (const float*)d_in[0];
    const int*   adj   = (const int*)d_in[1];
    const float* Wg    = (const float*)d_in[2];
    const float* a     = (const float*)d_in[3];
    const float* gamma = (const float*)d_in[4];
    const float* beta  = (const float*)d_in[5];
    const float* W1    = (const float*)d_in[6];
    const float* b1    = (const float*)d_in[7];
    const float* W2    = (const float*)d_in[8];
    const float* b2    = (const float*)d_in[9];
    const float* W3    = (const float*)d_in[10];
    const float* b3    = (const float*)d_in[11];
    float* out = (float*)d_out;

    char* ws = (char*)d_ws;
    float* Wh       = (float*)ws;                              // 1.5 MiB
    float* s        = (float*)(ws + (size_t)N * DH * 4);       // 32 KiB
    _Float16* WhT16 = (_Float16*)(ws + (size_t)N * DH * 4 + N * 4);   // 1 MiB
    float* accWs    = (float*)((char*)WhT16 + (size_t)64 * N * 2);    // 33.5 MiB
    unsigned long long* mask64 =
        (unsigned long long*)((char*)accWs + (size_t)NSPLIT * N * ACC_STRIDE * 4); // 8 MiB

    k_pack<<<N * (N / 64) / 256, 256, 0, stream>>>(adj, mask64);
    k_wh<<<N * DH / 256, 256, 0, stream>>>(x, Wg, Wh);
    k_s<<<N / 256, 256, 0, stream>>>(Wh, a, s);
    k_tr<<<64 * N / 256, 256, 0, stream>>>(Wh, WhT16);
    k_gat<<<64 * NSPLIT, 256, 0, stream>>>(mask64, WhT16, s, accWs);
    k_mlp<<<N / RB, 256, 0, stream>>>(accWs, gamma, beta, W1, b1, W2, b2, W3, b3, out);
}